// Round 1
// baseline (56.395 us; speedup 1.0000x reference)
//
#include <hip/hip_runtime.h>

// Problem constants
#define B_      128
#define N_WAY   5
#define QUERY   15
#define NUM_SLOT 32
#define H_      256
#define NS      (B_ * N_WAY)            // 640 support samples
#define NQ      (B_ * N_WAY * QUERY)    // 9600 query samples
#define ROW     (NUM_SLOT * H_)         // 8192 floats per sample
#define SPB     (N_WAY * QUERY)         // 75 query samples per batch

__device__ __forceinline__ float wave_reduce(float v) {
    for (int m = 32; m > 0; m >>= 1) v += __shfl_xor(v, m, 64);
    return v;
}

// K1: scores[sample][slot] = mean over H of out_f[sample][slot][:]
// one wave (64 lanes x float4) per row; 4 waves/block
__global__ void k_scores(const float* __restrict__ out_f, float* __restrict__ scores) {
    int wid = threadIdx.x >> 6, lane = threadIdx.x & 63;
    int row = blockIdx.x * 4 + wid;                 // 0 .. NS*NUM_SLOT-1 (20480)
    if (row >= NS * NUM_SLOT) return;
    const float4* p = (const float4*)(out_f + (size_t)row * H_);
    float4 v = p[lane];
    float s = wave_reduce(v.x + v.y + v.z + v.w);
    if (lane == 0) scores[row] = s * (1.0f / H_);
}

// K2: greedy max-select per batch (matches stable argsort + first-avail semantics)
__global__ void k_select(const float* __restrict__ scores, int* __restrict__ sel) {
    int b = blockIdx.x * blockDim.x + threadIdx.x;
    if (b >= B_) return;
    const float* sc = scores + (size_t)b * N_WAY * NUM_SLOT;
    unsigned used = 0u;
    for (int j = 0; j < N_WAY; ++j) {
        float best = -INFINITY; int bi = 0;
        for (int s = 0; s < NUM_SLOT; ++s) {
            if (!((used >> s) & 1u)) {
                float v = sc[j * NUM_SLOT + s];
                if (v > best) { best = v; bi = s; }   // strict > == first max (stable)
            }
        }
        used |= 1u << bi;
        sel[b * N_WAY + j] = bi;
    }
}

// K3: proto[b*5+k][:] = normalize(sup[b,k,sel[b,k],:]) ; one wave per row
__global__ void k_proto(const float* __restrict__ out_f, const int* __restrict__ sel,
                        float* __restrict__ proto) {
    int wid = threadIdx.x >> 6, lane = threadIdx.x & 63;
    int r = blockIdx.x * 4 + wid;                   // 0..639, r = b*5+k
    if (r >= NS) return;
    int slot = sel[r];
    const float4* p = (const float4*)(out_f + (size_t)r * ROW + (size_t)slot * H_);
    float4 v = p[lane];
    float s2 = wave_reduce(v.x*v.x + v.y*v.y + v.z*v.z + v.w*v.w);
    float inv = 1.0f / fmaxf(sqrtf(s2), 1e-12f);
    float4 o = make_float4(v.x*inv, v.y*inv, v.z*inv, v.w*inv);
    ((float4*)(proto + (size_t)r * H_))[lane] = o;
}

// K4: per query-sample wave: 5x {load qv slot row, joint reduce s2/dot/p2},
// then softmax-CE + argmin on lane 0. Writes per-sample nll & correct flags.
__global__ void k_main(const float* __restrict__ out_f, const int* __restrict__ sel,
                       const float* __restrict__ proto, const int* __restrict__ labels_q,
                       float* __restrict__ nll, float* __restrict__ corr) {
    int wid = threadIdx.x >> 6, lane = threadIdx.x & 63;
    int id = blockIdx.x * 4 + wid;                  // 0..9599
    if (id >= NQ) return;
    int b = id / SPB;
    const float* qrow = out_f + (size_t)(NS + id) * ROW;   // query sample row

    float diffs[N_WAY];
    #pragma unroll
    for (int k = 0; k < N_WAY; ++k) {
        int slot = sel[b * N_WAY + k];
        float4 qv = ((const float4*)(qrow + (size_t)slot * H_))[lane];
        float4 pv = ((const float4*)(proto + (size_t)(b * N_WAY + k) * H_))[lane];
        float s2 = qv.x*qv.x + qv.y*qv.y + qv.z*qv.z + qv.w*qv.w;
        float dt = qv.x*pv.x + qv.y*pv.y + qv.z*pv.z + qv.w*pv.w;
        float p2 = pv.x*pv.x + pv.y*pv.y + pv.z*pv.z + pv.w*pv.w;
        for (int m = 32; m > 0; m >>= 1) {
            s2 += __shfl_xor(s2, m, 64);
            dt += __shfl_xor(dt, m, 64);
            p2 += __shfl_xor(p2, m, 64);
        }
        float inv = 1.0f / fmaxf(sqrtf(s2), 1e-12f);
        diffs[k] = s2 * inv * inv - 2.0f * dt * inv + p2;
    }
    if (lane == 0) {
        int l = labels_q[id];                       // b*75 + (q'*5+w') == id
        float mn = diffs[0]; int am = 0;
        #pragma unroll
        for (int k = 1; k < N_WAY; ++k)
            if (diffs[k] < mn) { mn = diffs[k]; am = k; }   // first min == argmax logits
        float se = 0.0f;
        #pragma unroll
        for (int k = 0; k < N_WAY; ++k) se += expf(mn - diffs[k]);
        nll[id] = diffs[l] - mn + logf(se);
        corr[id] = (am == l) ? 1.0f : 0.0f;
    }
}

// K5: deterministic fixed-order reduction of nll/corr -> (loss, acc)
__global__ void k_finalize(const float* __restrict__ nll, const float* __restrict__ corr,
                           const float* __restrict__ att_loss, float* __restrict__ out) {
    __shared__ float sa[256], sb[256];
    int t = threadIdx.x;
    float a = 0.0f, c = 0.0f;
    for (int i = t; i < NQ; i += 256) { a += nll[i]; c += corr[i]; }
    sa[t] = a; sb[t] = c;
    __syncthreads();
    for (int off = 128; off > 0; off >>= 1) {
        if (t < off) { sa[t] += sa[t + off]; sb[t] += sb[t + off]; }
        __syncthreads();
    }
    if (t == 0) {
        out[0] = sa[0] * (1.0f / NQ) + att_loss[0];   // LAMBDA = 1.0
        out[1] = sb[0] * (1.0f / NQ);
    }
}

extern "C" void kernel_launch(void* const* d_in, const int* in_sizes, int n_in,
                              void* d_out, int out_size, void* d_ws, size_t ws_size,
                              hipStream_t stream) {
    const float* out_f    = (const float*)d_in[0];
    // d_in[1] = labels_support (unused by reference)
    const int*   labels_q = (const int*)d_in[2];
    const float* att_loss = (const float*)d_in[3];
    // d_in[4] = mode (unused)
    float* out = (float*)d_out;

    // workspace layout (floats)
    float* ws      = (float*)d_ws;
    float* scores  = ws;                     // 20480
    int*   sel     = (int*)(ws + 20480);     // 640
    float* proto   = ws + 21120;             // 163840
    float* nllv    = ws + 184960;            // 9600
    float* corrv   = ws + 194560;            // 9600   (total ~817 KB)

    k_scores  <<<(NS * NUM_SLOT) / 4, 256, 0, stream>>>(out_f, scores);
    k_select  <<<1, 128, 0, stream>>>(scores, sel);
    k_proto   <<<NS / 4, 256, 0, stream>>>(out_f, sel, proto);
    k_main    <<<NQ / 4, 256, 0, stream>>>(out_f, sel, proto, labels_q, nllv, corrv);
    k_finalize<<<1, 256, 0, stream>>>(nllv, corrv, att_loss, out);
}